// Round 4
// baseline (262.296 us; speedup 1.0000x reference)
//
#include <hip/hip_runtime.h>
#include <cstdint>
#include <cstddef>

// Problem constants
#define Bb 64
#define Ss 197
#define Dd 768
#define Pp 196
// Dead code: softmax over singleton axis -> attn==1 -> out = sampled_v.
// out[b,0,:]=1 ; out[b,1+p,:] = (sum_j w_j x[b,i_j,:]) @ Wv + (sum_j w_j) bv
// M = 12544 = 98*128, N = K = 768.

typedef short bf16x8 __attribute__((ext_vector_type(8)));
typedef short bf16x4 __attribute__((ext_vector_type(4)));
typedef float f32x4  __attribute__((ext_vector_type(4)));
struct alignas(16) F4 { float v[4]; };

__device__ __forceinline__ int mod_s(int v) {
    int r = v % Ss;
    return (r < 0) ? r + Ss : r;   // Python/JAX % semantics
}

__device__ __forceinline__ unsigned short f2bf(float f) {
    union { float f; unsigned u; } v; v.f = f;
    unsigned r = (v.u + 0x7FFFu + ((v.u >> 16) & 1u)) >> 16;  // RNE
    return (unsigned short)r;
}

struct GParams {
    float w0, w1, w2, w3;
    int i0, i1, i2, i3;
};

__device__ __forceinline__ GParams gather_params(
    const int* img_ids, const float* avgs, const float* stds,
    const float* noise, int b, int p)
{
    const int id = img_ids[b];
    const float a0 = avgs [((size_t)id * 2    ) * Pp + p];
    const float a1 = avgs [((size_t)id * 2 + 1) * Pp + p];
    const float s0 = stds [((size_t)id * 2    ) * Pp + p];
    const float s1 = stds [((size_t)id * 2 + 1) * Pp + p];
    const float nx = noise[((size_t)b  * 2    ) * Pp + p];
    const float ny = noise[((size_t)b  * 2 + 1) * Pp + p];
    const float kx = (nx - a0) / s0;
    const float ky = (ny - a1) / s1;
    const float cx = ceilf(kx),  fx = floorf(kx);
    const float cy = ceilf(ky),  fy = floorf(ky);
    const float dcx = 1.0f - fabsf(cx - kx);
    const float dfx = 1.0f - fabsf(fx - kx);
    const float dcy = 1.0f - fabsf(cy - ky);
    const float dfy = 1.0f - fabsf(fy - ky);
    GParams g;
    g.w0 = dcx * dcy;  g.w1 = dfx * dcy;  g.w2 = dcx * dfy;  g.w3 = dfx * dfy;
    g.i0 = mod_s((int)(14.0f * cy + cx));
    g.i1 = mod_s((int)(14.0f * cy + fx));
    g.i2 = mod_s((int)(14.0f * fy + cx));
    g.i3 = mod_s((int)(14.0f * fy + fx));
    return g;
}

// ================= prep: gather->Ag (bf16), Wv->WvT (bf16), cls rows =================
#define GATHER_BLKS 3136
#define TRANS_BLKS  144
#define CLS_BLKS    192

__global__ __launch_bounds__(256) void gsa_prep(
    const float* __restrict__ x,
    const int*   __restrict__ img_ids,
    const float* __restrict__ Wv,
    const float* __restrict__ avgs,
    const float* __restrict__ stds,
    const float* __restrict__ noise,
    unsigned short* __restrict__ Ag,    // (M,K) bf16
    unsigned short* __restrict__ WvT,   // (N,K) bf16
    float* __restrict__ wsB,            // (M,)
    float* __restrict__ out)
{
    __shared__ short T[64][66];
    const int t   = threadIdx.x;
    const int blk = blockIdx.x;

    if (blk < GATHER_BLKS) {
        const int lane = t & 63;
        const int w    = t >> 6;
        const int m    = blk * 4 + w;
        const int b    = m / Pp;
        const int p    = m - b * Pp;
        GParams g = gather_params(img_ids, avgs, stds, noise, b, p);
        const size_t xb = (size_t)b * Ss;
        const float* r0 = x + (xb + g.i0) * Dd;
        const float* r1 = x + (xb + g.i1) * Dd;
        const float* r2 = x + (xb + g.i2) * Dd;
        const float* r3 = x + (xb + g.i3) * Dd;
        unsigned short* dst = Ag + (size_t)m * Dd;
        #pragma unroll
        for (int c = 0; c < 3; ++c) {
            const int k = c * 256 + lane * 4;
            F4 v0 = *reinterpret_cast<const F4*>(r0 + k);
            F4 v1 = *reinterpret_cast<const F4*>(r1 + k);
            F4 v2 = *reinterpret_cast<const F4*>(r2 + k);
            F4 v3 = *reinterpret_cast<const F4*>(r3 + k);
            bf16x4 o;
            #pragma unroll
            for (int q = 0; q < 4; ++q)
                o[q] = (short)f2bf(g.w0*v0.v[q] + g.w1*v1.v[q] + g.w2*v2.v[q] + g.w3*v3.v[q]);
            *reinterpret_cast<bf16x4*>(dst + k) = o;
        }
        if (lane == 0) wsB[m] = g.w0 + g.w1 + g.w2 + g.w3;
    } else if (blk < GATHER_BLKS + TRANS_BLKS) {
        const int tb = blk - GATHER_BLKS;          // 12x12 tiles of 64x64
        const int k0 = (tb % 12) * 64;
        const int n0 = (tb / 12) * 64;
        const int tx = t & 63, tyy = t >> 6;
        #pragma unroll
        for (int pass = 0; pass < 16; ++pass) {
            const int i = pass * 4 + tyy;
            T[i][tx] = (short)f2bf(Wv[(size_t)(k0 + i) * Dd + n0 + tx]);
        }
        __syncthreads();
        #pragma unroll
        for (int pass = 0; pass < 16; ++pass) {
            const int n = pass * 4 + tyy;
            WvT[(size_t)(n0 + n) * Dd + k0 + tx] = (unsigned short)T[tx][n];
        }
    } else {
        const int idx = (blk - GATHER_BLKS - TRANS_BLKS) * 256 + t;  // < 49152
        const int b = idx / Dd;
        const int d = idx - b * Dd;
        out[(size_t)b * Ss * Dd + d] = 1.0f;
    }
}

// ================= barrier-free MFMA GEMM, n-fastest grid + depth-2 pipeline =================
__device__ __forceinline__ void load_frags(
    const unsigned short* const* ap, const unsigned short* const* bp, int kt,
    bf16x8 a[4], bf16x8 b[4])
{
    #pragma unroll
    for (int i = 0; i < 4; ++i) a[i] = *reinterpret_cast<const bf16x8*>(ap[i] + kt);
    #pragma unroll
    for (int i = 0; i < 4; ++i) b[i] = *reinterpret_cast<const bf16x8*>(bp[i] + kt);
}

__global__ __launch_bounds__(256) void gsa_gemm3(
    const unsigned short* __restrict__ Ag,    // (M,K)
    const unsigned short* __restrict__ WvT,   // (N,K)
    const float* __restrict__ wsB,
    const float* __restrict__ bv,
    float* __restrict__ out)
{
    const int t    = threadIdx.x;
    const int n0   = blockIdx.x * 128;   // n-tile FASTEST: same-m blocks co-dispatch
    const int m0   = blockIdx.y * 128;
    const int lane = t & 63;
    const int wv   = t >> 6;
    const int col  = lane & 15;
    const int quad = lane >> 4;
    const int wm   = (wv & 1) * 64;
    const int wn   = (wv >> 1) * 64;

    const unsigned short* ap[4];
    const unsigned short* bp[4];
    #pragma unroll
    for (int mi = 0; mi < 4; ++mi)
        ap[mi] = Ag + (size_t)(m0 + wm + mi * 16 + col) * Dd + quad * 8;
    #pragma unroll
    for (int ni = 0; ni < 4; ++ni)
        bp[ni] = WvT + (size_t)(n0 + wn + ni * 16 + col) * Dd + quad * 8;

    f32x4 acc[4][4];
    #pragma unroll
    for (int i = 0; i < 4; ++i)
        #pragma unroll
        for (int j = 0; j < 4; ++j) acc[i][j] = (f32x4)0.0f;

    // depth-2 software pipeline over 24 k-steps, fully unrolled (SSA renames copies away)
    bf16x8 a0[4], b0[4], a1[4], b1[4];
    load_frags(ap, bp, 0,  a0, b0);
    load_frags(ap, bp, 32, a1, b1);

    #pragma unroll
    for (int it = 0; it < 24; ++it) {
        const int ktn = it * 32 + 64;
        bf16x8 an[4], bn[4];
        if (ktn < Dd) load_frags(ap, bp, ktn, an, bn);
        if ((it & 1) == 0) {
            #pragma unroll
            for (int mi = 0; mi < 4; ++mi)
                #pragma unroll
                for (int ni = 0; ni < 4; ++ni)
                    acc[mi][ni] = __builtin_amdgcn_mfma_f32_16x16x32_bf16(
                        a0[mi], b0[ni], acc[mi][ni], 0, 0, 0);
            if (ktn < Dd) {
                #pragma unroll
                for (int i = 0; i < 4; ++i) { a0[i] = an[i]; b0[i] = bn[i]; }
            }
        } else {
            #pragma unroll
            for (int mi = 0; mi < 4; ++mi)
                #pragma unroll
                for (int ni = 0; ni < 4; ++ni)
                    acc[mi][ni] = __builtin_amdgcn_mfma_f32_16x16x32_bf16(
                        a1[mi], b1[ni], acc[mi][ni], 0, 0, 0);
            if (ktn < Dd) {
                #pragma unroll
                for (int i = 0; i < 4; ++i) { a1[i] = an[i]; b1[i] = bn[i]; }
            }
        }
    }

    float bvv[4];
    #pragma unroll
    for (int ni = 0; ni < 4; ++ni) bvv[ni] = bv[n0 + wn + ni * 16 + col];

    #pragma unroll
    for (int mi = 0; mi < 4; ++mi) {
        #pragma unroll
        for (int rg = 0; rg < 4; ++rg) {
            const int mg = m0 + wm + mi * 16 + quad * 4 + rg;  // C/D row = quad*4+reg
            const int b  = mg / Pp;
            const float wsv = wsB[mg];
            float* orow = out + ((size_t)(mg + b + 1)) * Dd;   // b*197 + 1 + p
            #pragma unroll
            for (int ni = 0; ni < 4; ++ni)
                orow[n0 + wn + ni * 16 + col] = acc[mi][ni][rg] + wsv * bvv[ni];
        }
    }
}

// ================= fallback: round-2 LDS MFMA path (ws >= 1.18MB only) =================
__global__ __launch_bounds__(256) void wv_transpose(
    const float* __restrict__ Wv, unsigned short* __restrict__ WvT)
{
    const int u = blockIdx.x * 256 + threadIdx.x;
    const int o = u * 8;
    const int n = o / Dd;
    const int k = o - n * Dd;
    bf16x8 tv;
    #pragma unroll
    for (int j = 0; j < 8; ++j) tv[j] = (short)f2bf(Wv[(size_t)(k + j) * Dd + n]);
    *reinterpret_cast<bf16x8*>(WvT + o) = tv;
}

__global__ __launch_bounds__(256) void gsa_fill_cls(float* __restrict__ out) {
    const int idx = blockIdx.x * 256 + threadIdx.x;
    if (idx < Bb * Dd) {
        const int b = idx / Dd;
        const int d = idx - b * Dd;
        out[(size_t)b * Ss * Dd + d] = 1.0f;
    }
}

__global__ __launch_bounds__(256, 2) void gsa_mfma(
    const float* __restrict__ x, const int* __restrict__ img_ids,
    const unsigned short* __restrict__ WvT, const float* __restrict__ bv,
    const float* __restrict__ avgs, const float* __restrict__ stds,
    const float* __restrict__ noise, float* __restrict__ out)
{
    __shared__ short As[128][40];
    __shared__ short Bs[128][40];
    __shared__ float wsums[128];
    const int t  = threadIdx.x;
    const int m0 = blockIdx.x * 128;
    const int n0 = blockIdx.y * 128;
    const int r  = t >> 1;
    const int kh = t & 1;
    const int ko = kh * 16;
    float w0, w1, w2, w3;
    const float *sA0, *sA1, *sA2, *sA3;
    {
        const int m = m0 + r, b = m / Pp, p = m - b * Pp;
        GParams g = gather_params(img_ids, avgs, stds, noise, b, p);
        w0 = g.w0; w1 = g.w1; w2 = g.w2; w3 = g.w3;
        const size_t xb = (size_t)b * Ss;
        sA0 = x + (xb + g.i0) * Dd + ko;
        sA1 = x + (xb + g.i1) * Dd + ko;
        sA2 = x + (xb + g.i2) * Dd + ko;
        sA3 = x + (xb + g.i3) * Dd + ko;
        if (kh == 0) wsums[r] = w0 + w1 + w2 + w3;
    }
    const unsigned short* srcB = WvT + (size_t)(n0 + r) * Dd + ko;
    const int lane = t & 63, wv = t >> 6;
    const int col = lane & 15, quad = lane >> 4;
    const int wm = (wv & 1) * 64, wn = (wv >> 1) * 64;
    const short* aptr[4];
    const short* bptr[4];
    #pragma unroll
    for (int mi = 0; mi < 4; ++mi) aptr[mi] = &As[wm + mi * 16 + col][quad * 8];
    #pragma unroll
    for (int ni = 0; ni < 4; ++ni) bptr[ni] = &Bs[wn + ni * 16 + col][quad * 8];
    f32x4 acc[4][4];
    #pragma unroll
    for (int i = 0; i < 4; ++i)
        #pragma unroll
        for (int j = 0; j < 4; ++j) acc[i][j] = (f32x4)0.0f;
    #pragma unroll 1
    for (int kt = 0; kt < Dd; kt += 32) {
        F4 l0[4], l1[4], l2[4], l3[4];
        #pragma unroll
        for (int c = 0; c < 4; ++c) {
            l0[c] = *reinterpret_cast<const F4*>(sA0 + kt + c * 4);
            l1[c] = *reinterpret_cast<const F4*>(sA1 + kt + c * 4);
            l2[c] = *reinterpret_cast<const F4*>(sA2 + kt + c * 4);
            l3[c] = *reinterpret_cast<const F4*>(sA3 + kt + c * 4);
        }
        bf16x8 b0 = *reinterpret_cast<const bf16x8*>(srcB + kt);
        bf16x8 b1 = *reinterpret_cast<const bf16x8*>(srcB + kt + 8);
        bf16x8 ua0, ua1;
        #pragma unroll
        for (int e = 0; e < 8; ++e) {
            const int c = e >> 2, q = e & 3;
            ua0[e] = (short)f2bf(w0*l0[c].v[q] + w1*l1[c].v[q] + w2*l2[c].v[q] + w3*l3[c].v[q]);
        }
        #pragma unroll
        for (int e = 0; e < 8; ++e) {
            const int c = (e + 8) >> 2, q = e & 3;
            ua1[e] = (short)f2bf(w0*l0[c].v[q] + w1*l1[c].v[q] + w2*l2[c].v[q] + w3*l3[c].v[q]);
        }
        __syncthreads();
        *reinterpret_cast<bf16x8*>(&As[r][ko])     = ua0;
        *reinterpret_cast<bf16x8*>(&As[r][ko + 8]) = ua1;
        *reinterpret_cast<bf16x8*>(&Bs[r][ko])     = b0;
        *reinterpret_cast<bf16x8*>(&Bs[r][ko + 8]) = b1;
        __syncthreads();
        bf16x8 aF[4], bF[4];
        #pragma unroll
        for (int mi = 0; mi < 4; ++mi) aF[mi] = *reinterpret_cast<const bf16x8*>(aptr[mi]);
        #pragma unroll
        for (int ni = 0; ni < 4; ++ni) bF[ni] = *reinterpret_cast<const bf16x8*>(bptr[ni]);
        #pragma unroll
        for (int mi = 0; mi < 4; ++mi)
            #pragma unroll
            for (int ni = 0; ni < 4; ++ni)
                acc[mi][ni] = __builtin_amdgcn_mfma_f32_16x16x32_bf16(
                    aF[mi], bF[ni], acc[mi][ni], 0, 0, 0);
    }
    float bvv[4];
    #pragma unroll
    for (int ni = 0; ni < 4; ++ni) bvv[ni] = bv[n0 + wn + ni * 16 + col];
    #pragma unroll
    for (int mi = 0; mi < 4; ++mi) {
        #pragma unroll
        for (int rg = 0; rg < 4; ++rg) {
            const int ml = wm + mi * 16 + quad * 4 + rg;
            const int mg = m0 + ml;
            const int b  = mg / Pp;
            const float wsv = wsums[ml];
            float* orow = out + ((size_t)(mg + b + 1)) * Dd;
            #pragma unroll
            for (int ni = 0; ni < 4; ++ni)
                orow[n0 + wn + ni * 16 + col] = acc[mi][ni][rg] + wsv * bvv[ni];
        }
    }
}

extern "C" void kernel_launch(void* const* d_in, const int* in_sizes, int n_in,
                              void* d_out, int out_size, void* d_ws, size_t ws_size,
                              hipStream_t stream) {
    // order: x, img_ids, mask, Wq, bq, Wk, bk, Wv, bv, avgs, std_devs, noise
    const float* x       = (const float*)d_in[0];
    const int*   img_ids = (const int*)  d_in[1];
    const float* Wv      = (const float*)d_in[7];
    const float* bv      = (const float*)d_in[8];
    const float* avgs    = (const float*)d_in[9];
    const float* stds    = (const float*)d_in[10];
    const float* noise   = (const float*)d_in[11];
    float* out = (float*)d_out;

    const size_t ag_bytes  = (size_t)Bb * Pp * Dd * sizeof(unsigned short); // 19.27 MB
    const size_t wvt_bytes = (size_t)Dd * Dd * sizeof(unsigned short);      // 1.18 MB
    const size_t ws_need   = ag_bytes + wvt_bytes + (size_t)Bb * Pp * sizeof(float);

    if (d_ws != nullptr && ws_size >= ws_need) {
        unsigned short* Ag  = (unsigned short*)d_ws;
        unsigned short* WvT = (unsigned short*)((char*)d_ws + ag_bytes);
        float*          wsB = (float*)((char*)d_ws + ag_bytes + wvt_bytes);
        gsa_prep<<<GATHER_BLKS + TRANS_BLKS + CLS_BLKS, 256, 0, stream>>>(
            x, img_ids, Wv, avgs, stds, noise, Ag, WvT, wsB, out);
        dim3 grid(Dd / 128, (Bb * Pp) / 128);   // (6, 98): n varies fastest
        gsa_gemm3<<<grid, 256, 0, stream>>>(Ag, WvT, wsB, bv, out);
    } else {
        unsigned short* WvT = (unsigned short*)d_ws;
        gsa_fill_cls<<<(Bb * Dd + 255) / 256, 256, 0, stream>>>(out);
        wv_transpose<<<(Dd * Dd / 8) / 256, 256, 0, stream>>>(Wv, WvT);
        dim3 grid((Bb * Pp) / 128, Dd / 128);
        gsa_mfma<<<grid, 256, 0, stream>>>(x, img_ids, WvT, bv, avgs, stds, noise, out);
    }
}

// Round 5
// 215.504 us; speedup vs baseline: 1.2171x; 1.2171x over previous
//
#include <hip/hip_runtime.h>
#include <cstdint>
#include <cstddef>

// Problem constants
#define Bb 64
#define Ss 197
#define Dd 768
#define Pp 196
// Dead code: softmax over singleton axis -> attn==1 -> out = sampled_v.
// out[b,0,:]=1 ; out[b,1+p,:] = (sum_j w_j x[b,i_j,:]) @ Wv + (sum_j w_j) bv
// M = 12544 = 98*128, N = K = 768.

typedef short bf16x8 __attribute__((ext_vector_type(8)));
typedef short bf16x4 __attribute__((ext_vector_type(4)));
typedef float f32x4  __attribute__((ext_vector_type(4)));
struct alignas(16) F4 { float v[4]; };

__device__ __forceinline__ int mod_s(int v) {
    int r = v % Ss;
    return (r < 0) ? r + Ss : r;   // Python/JAX % semantics
}

__device__ __forceinline__ unsigned short f2bf(float f) {
    union { float f; unsigned u; } v; v.f = f;
    unsigned r = (v.u + 0x7FFFu + ((v.u >> 16) & 1u)) >> 16;  // RNE
    return (unsigned short)r;
}

// async global->LDS DMA, 16B per lane; LDS dest = wave-uniform base + lane*16
__device__ __forceinline__ void gload_lds16(const void* g, void* l) {
    __builtin_amdgcn_global_load_lds(
        (const __attribute__((address_space(1))) unsigned int*)g,
        (__attribute__((address_space(3))) unsigned int*)l, 16, 0, 0);
}

struct GParams {
    float w0, w1, w2, w3;
    int i0, i1, i2, i3;
};

__device__ __forceinline__ GParams gather_params(
    const int* img_ids, const float* avgs, const float* stds,
    const float* noise, int b, int p)
{
    const int id = img_ids[b];
    const float a0 = avgs [((size_t)id * 2    ) * Pp + p];
    const float a1 = avgs [((size_t)id * 2 + 1) * Pp + p];
    const float s0 = stds [((size_t)id * 2    ) * Pp + p];
    const float s1 = stds [((size_t)id * 2 + 1) * Pp + p];
    const float nx = noise[((size_t)b  * 2    ) * Pp + p];
    const float ny = noise[((size_t)b  * 2 + 1) * Pp + p];
    const float kx = (nx - a0) / s0;
    const float ky = (ny - a1) / s1;
    const float cx = ceilf(kx),  fx = floorf(kx);
    const float cy = ceilf(ky),  fy = floorf(ky);
    const float dcx = 1.0f - fabsf(cx - kx);
    const float dfx = 1.0f - fabsf(fx - kx);
    const float dcy = 1.0f - fabsf(cy - ky);
    const float dfy = 1.0f - fabsf(fy - ky);
    GParams g;
    g.w0 = dcx * dcy;  g.w1 = dfx * dcy;  g.w2 = dcx * dfy;  g.w3 = dfx * dfy;
    g.i0 = mod_s((int)(14.0f * cy + cx));
    g.i1 = mod_s((int)(14.0f * cy + fx));
    g.i2 = mod_s((int)(14.0f * fy + cx));
    g.i3 = mod_s((int)(14.0f * fy + fx));
    return g;
}

// ================= prep: gather->Ag (bf16), Wv->WvT (bf16), cls rows =================
#define GATHER_BLKS 3136
#define TRANS_BLKS  144
#define CLS_BLKS    192

__global__ __launch_bounds__(256) void gsa_prep(
    const float* __restrict__ x,
    const int*   __restrict__ img_ids,
    const float* __restrict__ Wv,
    const float* __restrict__ avgs,
    const float* __restrict__ stds,
    const float* __restrict__ noise,
    unsigned short* __restrict__ Ag,    // (M,K) bf16
    unsigned short* __restrict__ WvT,   // (N,K) bf16
    float* __restrict__ wsB,            // (M,)
    float* __restrict__ out)
{
    __shared__ short T[64][66];
    const int t   = threadIdx.x;
    const int blk = blockIdx.x;

    if (blk < GATHER_BLKS) {
        const int lane = t & 63;
        const int w    = t >> 6;
        const int m    = blk * 4 + w;
        const int b    = m / Pp;
        const int p    = m - b * Pp;
        GParams g = gather_params(img_ids, avgs, stds, noise, b, p);
        const size_t xb = (size_t)b * Ss;
        const float* r0 = x + (xb + g.i0) * Dd;
        const float* r1 = x + (xb + g.i1) * Dd;
        const float* r2 = x + (xb + g.i2) * Dd;
        const float* r3 = x + (xb + g.i3) * Dd;
        unsigned short* dst = Ag + (size_t)m * Dd;
        #pragma unroll
        for (int c = 0; c < 3; ++c) {
            const int k = c * 256 + lane * 4;
            F4 v0 = *reinterpret_cast<const F4*>(r0 + k);
            F4 v1 = *reinterpret_cast<const F4*>(r1 + k);
            F4 v2 = *reinterpret_cast<const F4*>(r2 + k);
            F4 v3 = *reinterpret_cast<const F4*>(r3 + k);
            bf16x4 o;
            #pragma unroll
            for (int q = 0; q < 4; ++q)
                o[q] = (short)f2bf(g.w0*v0.v[q] + g.w1*v1.v[q] + g.w2*v2.v[q] + g.w3*v3.v[q]);
            *reinterpret_cast<bf16x4*>(dst + k) = o;
        }
        if (lane == 0) wsB[m] = g.w0 + g.w1 + g.w2 + g.w3;
    } else if (blk < GATHER_BLKS + TRANS_BLKS) {
        const int tb = blk - GATHER_BLKS;          // 12x12 tiles of 64x64
        const int k0 = (tb % 12) * 64;
        const int n0 = (tb / 12) * 64;
        const int tx = t & 63, tyy = t >> 6;
        #pragma unroll
        for (int pass = 0; pass < 16; ++pass) {
            const int i = pass * 4 + tyy;
            T[i][tx] = (short)f2bf(Wv[(size_t)(k0 + i) * Dd + n0 + tx]);
        }
        __syncthreads();
        #pragma unroll
        for (int pass = 0; pass < 16; ++pass) {
            const int n = pass * 4 + tyy;
            WvT[(size_t)(n0 + n) * Dd + k0 + tx] = (unsigned short)T[tx][n];
        }
    } else {
        const int idx = (blk - GATHER_BLKS - TRANS_BLKS) * 256 + t;  // < 49152
        const int b = idx / Dd;
        const int d = idx - b * Dd;
        out[(size_t)b * Ss * Dd + d] = 1.0f;
    }
}

// ================= MFMA GEMM: LDS double-buffer via global_load_lds, XCD-partitioned ====
// Tile 128x128, BK=64, 256 thr / 4 waves (2x2 of 64x64). 12 stages.
// LDS chunk swizzle: 16B chunk q of row r stored at slot r*8 + (q ^ (r&7)).
#define NSTG 12

__global__ __launch_bounds__(256, 2) void gsa_gemm4(
    const unsigned short* __restrict__ Ag,    // (M,K)
    const unsigned short* __restrict__ WvT,   // (N,K)
    const float* __restrict__ wsB,
    const float* __restrict__ bv,
    float* __restrict__ out)
{
    __shared__ short lds[2][16384];   // [buf]: A = [0,8192), B = [8192,16384)

    const int t = threadIdx.x;
    // XCD partition: xcd = L&7 owns m-tiles {xcd, xcd+8, ...}; n varies fastest.
    const int L      = blockIdx.x;
    const int xcd    = L & 7;
    const int grp    = L >> 3;          // 0..77
    const int n_t    = grp % 6;
    const int mchunk = grp / 6;         // 0..12
    const int m_tile = mchunk * 8 + xcd;
    if (m_tile >= 98) return;           // 36 of 624 blocks idle
    const int m0 = m_tile * 128;
    const int n0 = n_t * 128;

    const int lane = t & 63;
    const int w    = t >> 6;

    // ---- staging: per wave 4 A-insts + 4 B-insts of 1KB (8 rows x 64B... 8 rows x 128B) ----
    const unsigned short* aSrc[4];
    const unsigned short* bSrc[4];
    int ldsA[4], ldsB[4];
    #pragma unroll
    for (int i = 0; i < 4; ++i) {
        const int rr = (w * 4 + i) * 8 + (lane >> 3);   // row 0..127
        const int qq = (lane & 7) ^ (rr & 7);           // swizzled global chunk
        aSrc[i] = Ag  + (size_t)(m0 + rr) * Dd + qq * 8;
        bSrc[i] = WvT + (size_t)(n0 + rr) * Dd + qq * 8;
        ldsA[i] = (w * 4 + i) * 512;           // shorts (wave-uniform)
        ldsB[i] = 8192 + (w * 4 + i) * 512;
    }

    // ---- MFMA fragment offsets (swizzle-aware) ----
    const int col  = lane & 15;
    const int quad = lane >> 4;
    const int wm   = (w & 1) * 64;
    const int wn   = (w >> 1) * 64;
    int offA[4][2], offB[4][2];
    #pragma unroll
    for (int i = 0; i < 4; ++i) {
        const int ra = wm + i * 16 + col;
        const int rb = wn + i * 16 + col;
        #pragma unroll
        for (int ks = 0; ks < 2; ++ks) {
            offA[i][ks] = (ra * 8 + ((ks * 4 + quad) ^ (ra & 7))) * 8;
            offB[i][ks] = 8192 + (rb * 8 + ((ks * 4 + quad) ^ (rb & 7))) * 8;
        }
    }

    f32x4 acc[4][4];
    #pragma unroll
    for (int i = 0; i < 4; ++i)
        #pragma unroll
        for (int j = 0; j < 4; ++j) acc[i][j] = (f32x4)0.0f;

    // stage 0 into buf 0
    #pragma unroll
    for (int i = 0; i < 4; ++i) {
        gload_lds16(aSrc[i], &lds[0][ldsA[i]]);
        gload_lds16(bSrc[i], &lds[0][ldsB[i]]);
    }
    __syncthreads();   // vmcnt(0) drain: stage 0 resident

    for (int s = 0; s < NSTG; ++s) {
        if (s + 1 < NSTG) {
            const int kadv = (s + 1) * 64;
            short* nbuf = lds[(s + 1) & 1];
            #pragma unroll
            for (int i = 0; i < 4; ++i) {
                gload_lds16(aSrc[i] + kadv, &nbuf[ldsA[i]]);
                gload_lds16(bSrc[i] + kadv, &nbuf[ldsB[i]]);
            }
        }
        const short* base = lds[s & 1];
        #pragma unroll
        for (int ks = 0; ks < 2; ++ks) {
            bf16x8 aF[4], bF[4];
            #pragma unroll
            for (int mi = 0; mi < 4; ++mi)
                aF[mi] = *reinterpret_cast<const bf16x8*>(base + offA[mi][ks]);
            #pragma unroll
            for (int ni = 0; ni < 4; ++ni)
                bF[ni] = *reinterpret_cast<const bf16x8*>(base + offB[ni][ks]);
            #pragma unroll
            for (int mi = 0; mi < 4; ++mi)
                #pragma unroll
                for (int ni = 0; ni < 4; ++ni)
                    acc[mi][ni] = __builtin_amdgcn_mfma_f32_16x16x32_bf16(
                        aF[mi], bF[ni], acc[mi][ni], 0, 0, 0);
        }
        __syncthreads();   // drains next-stage DMAs + guards buffer reuse
    }

    // ---- epilogue ----
    float bvv[4];
    #pragma unroll
    for (int ni = 0; ni < 4; ++ni) bvv[ni] = bv[n0 + wn + ni * 16 + col];

    #pragma unroll
    for (int mi = 0; mi < 4; ++mi) {
        #pragma unroll
        for (int rg = 0; rg < 4; ++rg) {
            const int mg = m0 + wm + mi * 16 + quad * 4 + rg;  // C/D row = quad*4+reg
            const int b  = mg / Pp;
            const float wsv = wsB[mg];
            float* orow = out + ((size_t)(mg + b + 1)) * Dd;   // b*197 + 1 + p
            #pragma unroll
            for (int ni = 0; ni < 4; ++ni)
                orow[n0 + wn + ni * 16 + col] = acc[mi][ni][rg] + wsv * bvv[ni];
        }
    }
}

// ================= fallback: round-2 LDS MFMA path (ws >= 1.18MB only) =================
__global__ __launch_bounds__(256) void wv_transpose(
    const float* __restrict__ Wv, unsigned short* __restrict__ WvT)
{
    const int u = blockIdx.x * 256 + threadIdx.x;
    const int o = u * 8;
    const int n = o / Dd;
    const int k = o - n * Dd;
    bf16x8 tv;
    #pragma unroll
    for (int j = 0; j < 8; ++j) tv[j] = (short)f2bf(Wv[(size_t)(k + j) * Dd + n]);
    *reinterpret_cast<bf16x8*>(WvT + o) = tv;
}

__global__ __launch_bounds__(256) void gsa_fill_cls(float* __restrict__ out) {
    const int idx = blockIdx.x * 256 + threadIdx.x;
    if (idx < Bb * Dd) {
        const int b = idx / Dd;
        const int d = idx - b * Dd;
        out[(size_t)b * Ss * Dd + d] = 1.0f;
    }
}

__global__ __launch_bounds__(256, 2) void gsa_mfma(
    const float* __restrict__ x, const int* __restrict__ img_ids,
    const unsigned short* __restrict__ WvT, const float* __restrict__ bv,
    const float* __restrict__ avgs, const float* __restrict__ stds,
    const float* __restrict__ noise, float* __restrict__ out)
{
    __shared__ short As[128][40];
    __shared__ short Bs[128][40];
    __shared__ float wsums[128];
    const int t  = threadIdx.x;
    const int m0 = blockIdx.x * 128;
    const int n0 = blockIdx.y * 128;
    const int r  = t >> 1;
    const int kh = t & 1;
    const int ko = kh * 16;
    float w0, w1, w2, w3;
    const float *sA0, *sA1, *sA2, *sA3;
    {
        const int m = m0 + r, b = m / Pp, p = m - b * Pp;
        GParams g = gather_params(img_ids, avgs, stds, noise, b, p);
        w0 = g.w0; w1 = g.w1; w2 = g.w2; w3 = g.w3;
        const size_t xb = (size_t)b * Ss;
        sA0 = x + (xb + g.i0) * Dd + ko;
        sA1 = x + (xb + g.i1) * Dd + ko;
        sA2 = x + (xb + g.i2) * Dd + ko;
        sA3 = x + (xb + g.i3) * Dd + ko;
        if (kh == 0) wsums[r] = w0 + w1 + w2 + w3;
    }
    const unsigned short* srcB = WvT + (size_t)(n0 + r) * Dd + ko;
    const int lane = t & 63, wv = t >> 6;
    const int col = lane & 15, quad = lane >> 4;
    const int wm = (wv & 1) * 64, wn = (wv >> 1) * 64;
    const short* aptr[4];
    const short* bptr[4];
    #pragma unroll
    for (int mi = 0; mi < 4; ++mi) aptr[mi] = &As[wm + mi * 16 + col][quad * 8];
    #pragma unroll
    for (int ni = 0; ni < 4; ++ni) bptr[ni] = &Bs[wn + ni * 16 + col][quad * 8];
    f32x4 acc[4][4];
    #pragma unroll
    for (int i = 0; i < 4; ++i)
        #pragma unroll
        for (int j = 0; j < 4; ++j) acc[i][j] = (f32x4)0.0f;
    #pragma unroll 1
    for (int kt = 0; kt < Dd; kt += 32) {
        F4 l0[4], l1[4], l2[4], l3[4];
        #pragma unroll
        for (int c = 0; c < 4; ++c) {
            l0[c] = *reinterpret_cast<const F4*>(sA0 + kt + c * 4);
            l1[c] = *reinterpret_cast<const F4*>(sA1 + kt + c * 4);
            l2[c] = *reinterpret_cast<const F4*>(sA2 + kt + c * 4);
            l3[c] = *reinterpret_cast<const F4*>(sA3 + kt + c * 4);
        }
        bf16x8 b0 = *reinterpret_cast<const bf16x8*>(srcB + kt);
        bf16x8 b1 = *reinterpret_cast<const bf16x8*>(srcB + kt + 8);
        bf16x8 ua0, ua1;
        #pragma unroll
        for (int e = 0; e < 8; ++e) {
            const int c = e >> 2, q = e & 3;
            ua0[e] = (short)f2bf(w0*l0[c].v[q] + w1*l1[c].v[q] + w2*l2[c].v[q] + w3*l3[c].v[q]);
        }
        #pragma unroll
        for (int e = 0; e < 8; ++e) {
            const int c = (e + 8) >> 2, q = e & 3;
            ua1[e] = (short)f2bf(w0*l0[c].v[q] + w1*l1[c].v[q] + w2*l2[c].v[q] + w3*l3[c].v[q]);
        }
        __syncthreads();
        *reinterpret_cast<bf16x8*>(&As[r][ko])     = ua0;
        *reinterpret_cast<bf16x8*>(&As[r][ko + 8]) = ua1;
        *reinterpret_cast<bf16x8*>(&Bs[r][ko])     = b0;
        *reinterpret_cast<bf16x8*>(&Bs[r][ko + 8]) = b1;
        __syncthreads();
        bf16x8 aF[4], bF[4];
        #pragma unroll
        for (int mi = 0; mi < 4; ++mi) aF[mi] = *reinterpret_cast<const bf16x8*>(aptr[mi]);
        #pragma unroll
        for (int ni = 0; ni < 4; ++ni) bF[ni] = *reinterpret_cast<const bf16x8*>(bptr[ni]);
        #pragma unroll
        for (int mi = 0; mi < 4; ++mi)
            #pragma unroll
            for (int ni = 0; ni < 4; ++ni)
                acc[mi][ni] = __builtin_amdgcn_mfma_f32_16x16x32_bf16(
                    aF[mi], bF[ni], acc[mi][ni], 0, 0, 0);
    }
    float bvv[4];
    #pragma unroll
    for (int ni = 0; ni < 4; ++ni) bvv[ni] = bv[n0 + wn + ni * 16 + col];
    #pragma unroll
    for (int mi = 0; mi < 4; ++mi) {
        #pragma unroll
        for (int rg = 0; rg < 4; ++rg) {
            const int ml = wm + mi * 16 + quad * 4 + rg;
            const int mg = m0 + ml;
            const int b  = mg / Pp;
            const float wsv = wsums[ml];
            float* orow = out + ((size_t)(mg + b + 1)) * Dd;
            #pragma unroll
            for (int ni = 0; ni < 4; ++ni)
                orow[n0 + wn + ni * 16 + col] = acc[mi][ni][rg] + wsv * bvv[ni];
        }
    }
}

extern "C" void kernel_launch(void* const* d_in, const int* in_sizes, int n_in,
                              void* d_out, int out_size, void* d_ws, size_t ws_size,
                              hipStream_t stream) {
    // order: x, img_ids, mask, Wq, bq, Wk, bk, Wv, bv, avgs, std_devs, noise
    const float* x       = (const float*)d_in[0];
    const int*   img_ids = (const int*)  d_in[1];
    const float* Wv      = (const float*)d_in[7];
    const float* bv      = (const float*)d_in[8];
    const float* avgs    = (const float*)d_in[9];
    const float* stds    = (const float*)d_in[10];
    const float* noise   = (const float*)d_in[11];
    float* out = (float*)d_out;

    const size_t ag_bytes  = (size_t)Bb * Pp * Dd * sizeof(unsigned short); // 19.27 MB
    const size_t wvt_bytes = (size_t)Dd * Dd * sizeof(unsigned short);      // 1.18 MB
    const size_t ws_need   = ag_bytes + wvt_bytes + (size_t)Bb * Pp * sizeof(float);

    if (d_ws != nullptr && ws_size >= ws_need) {
        unsigned short* Ag  = (unsigned short*)d_ws;
        unsigned short* WvT = (unsigned short*)((char*)d_ws + ag_bytes);
        float*          wsB = (float*)((char*)d_ws + ag_bytes + wvt_bytes);
        gsa_prep<<<GATHER_BLKS + TRANS_BLKS + CLS_BLKS, 256, 0, stream>>>(
            x, img_ids, Wv, avgs, stds, noise, Ag, WvT, wsB, out);
        gsa_gemm4<<<624, 256, 0, stream>>>(Ag, WvT, wsB, bv, out);  // 13*6*8, XCD-swizzled
    } else {
        unsigned short* WvT = (unsigned short*)d_ws;
        gsa_fill_cls<<<(Bb * Dd + 255) / 256, 256, 0, stream>>>(out);
        wv_transpose<<<(Dd * Dd / 8) / 256, 256, 0, stream>>>(Wv, WvT);
        dim3 grid((Bb * Pp) / 128, Dd / 128);
        gsa_mfma<<<grid, 256, 0, stream>>>(x, img_ids, WvT, bv, avgs, stds, noise, out);
    }
}

// Round 6
// 213.217 us; speedup vs baseline: 1.2302x; 1.0107x over previous
//
#include <hip/hip_runtime.h>
#include <cstdint>
#include <cstddef>

// Problem constants
#define Bb 64
#define Ss 197
#define Dd 768
#define Pp 196
// Dead code: softmax over singleton axis -> attn==1 -> out = sampled_v.
// out[b,0,:]=1 ; out[b,1+p,:] = (sum_j w_j x[b,i_j,:]) @ Wv + (sum_j w_j) bv
// M = 12544 = 98*128, N = K = 768.

typedef short bf16x8 __attribute__((ext_vector_type(8)));
typedef short bf16x4 __attribute__((ext_vector_type(4)));
typedef float f32x4  __attribute__((ext_vector_type(4)));
struct alignas(16) F4 { float v[4]; };

__device__ __forceinline__ int mod_s(int v) {
    int r = v % Ss;
    return (r < 0) ? r + Ss : r;   // Python/JAX % semantics
}

__device__ __forceinline__ unsigned short f2bf(float f) {
    union { float f; unsigned u; } v; v.f = f;
    unsigned r = (v.u + 0x7FFFu + ((v.u >> 16) & 1u)) >> 16;  // RNE
    return (unsigned short)r;
}

// async global->LDS DMA, 16B per lane; LDS dest = wave-uniform base + lane*16
__device__ __forceinline__ void gload_lds16(const void* g, void* l) {
    __builtin_amdgcn_global_load_lds(
        (const __attribute__((address_space(1))) unsigned int*)g,
        (__attribute__((address_space(3))) unsigned int*)l, 16, 0, 0);
}

struct GParams {
    float w0, w1, w2, w3;
    int i0, i1, i2, i3;
};

__device__ __forceinline__ GParams gather_params(
    const int* img_ids, const float* avgs, const float* stds,
    const float* noise, int b, int p)
{
    const int id = img_ids[b];
    const float a0 = avgs [((size_t)id * 2    ) * Pp + p];
    const float a1 = avgs [((size_t)id * 2 + 1) * Pp + p];
    const float s0 = stds [((size_t)id * 2    ) * Pp + p];
    const float s1 = stds [((size_t)id * 2 + 1) * Pp + p];
    const float nx = noise[((size_t)b  * 2    ) * Pp + p];
    const float ny = noise[((size_t)b  * 2 + 1) * Pp + p];
    const float kx = (nx - a0) / s0;
    const float ky = (ny - a1) / s1;
    const float cx = ceilf(kx),  fx = floorf(kx);
    const float cy = ceilf(ky),  fy = floorf(ky);
    const float dcx = 1.0f - fabsf(cx - kx);
    const float dfx = 1.0f - fabsf(fx - kx);
    const float dcy = 1.0f - fabsf(cy - ky);
    const float dfy = 1.0f - fabsf(fy - ky);
    GParams g;
    g.w0 = dcx * dcy;  g.w1 = dfx * dcy;  g.w2 = dcx * dfy;  g.w3 = dfx * dfy;
    g.i0 = mod_s((int)(14.0f * cy + cx));
    g.i1 = mod_s((int)(14.0f * cy + fx));
    g.i2 = mod_s((int)(14.0f * fy + cx));
    g.i3 = mod_s((int)(14.0f * fy + fx));
    return g;
}

// ================= prep: gather->Ag (bf16), Wv->WvT (bf16), cls rows =================
#define GATHER_BLKS 3136
#define TRANS_BLKS  144
#define CLS_BLKS    192

__global__ __launch_bounds__(256) void gsa_prep(
    const float* __restrict__ x,
    const int*   __restrict__ img_ids,
    const float* __restrict__ Wv,
    const float* __restrict__ avgs,
    const float* __restrict__ stds,
    const float* __restrict__ noise,
    unsigned short* __restrict__ Ag,    // (M,K) bf16
    unsigned short* __restrict__ WvT,   // (N,K) bf16
    float* __restrict__ wsB,            // (M,)
    float* __restrict__ out)
{
    __shared__ short T[64][66];
    const int t   = threadIdx.x;
    const int blk = blockIdx.x;

    if (blk < GATHER_BLKS) {
        const int lane = t & 63;
        const int w    = t >> 6;
        const int m    = blk * 4 + w;
        const int b    = m / Pp;
        const int p    = m - b * Pp;
        GParams g = gather_params(img_ids, avgs, stds, noise, b, p);
        const size_t xb = (size_t)b * Ss;
        const float* r0 = x + (xb + g.i0) * Dd;
        const float* r1 = x + (xb + g.i1) * Dd;
        const float* r2 = x + (xb + g.i2) * Dd;
        const float* r3 = x + (xb + g.i3) * Dd;
        unsigned short* dst = Ag + (size_t)m * Dd;
        #pragma unroll
        for (int c = 0; c < 3; ++c) {
            const int k = c * 256 + lane * 4;
            F4 v0 = *reinterpret_cast<const F4*>(r0 + k);
            F4 v1 = *reinterpret_cast<const F4*>(r1 + k);
            F4 v2 = *reinterpret_cast<const F4*>(r2 + k);
            F4 v3 = *reinterpret_cast<const F4*>(r3 + k);
            bf16x4 o;
            #pragma unroll
            for (int q = 0; q < 4; ++q)
                o[q] = (short)f2bf(g.w0*v0.v[q] + g.w1*v1.v[q] + g.w2*v2.v[q] + g.w3*v3.v[q]);
            *reinterpret_cast<bf16x4*>(dst + k) = o;
        }
        if (lane == 0) wsB[m] = g.w0 + g.w1 + g.w2 + g.w3;
    } else if (blk < GATHER_BLKS + TRANS_BLKS) {
        const int tb = blk - GATHER_BLKS;          // 12x12 tiles of 64x64
        const int k0 = (tb % 12) * 64;
        const int n0 = (tb / 12) * 64;
        const int tx = t & 63, tyy = t >> 6;
        #pragma unroll
        for (int pass = 0; pass < 16; ++pass) {
            const int i = pass * 4 + tyy;
            T[i][tx] = (short)f2bf(Wv[(size_t)(k0 + i) * Dd + n0 + tx]);
        }
        __syncthreads();
        #pragma unroll
        for (int pass = 0; pass < 16; ++pass) {
            const int n = pass * 4 + tyy;
            WvT[(size_t)(n0 + n) * Dd + k0 + tx] = (unsigned short)T[tx][n];
        }
    } else {
        const int idx = (blk - GATHER_BLKS - TRANS_BLKS) * 256 + t;  // < 49152
        const int b = idx / Dd;
        const int d = idx - b * Dd;
        out[(size_t)b * Ss * Dd + d] = 1.0f;
    }
}

// ===== MFMA GEMM: m97-style single-buffer global_load_lds, XCD-partitioned =====
// Tile 128x128, BK=64, 256 thr / 4 waves (2x2 of 64x64). 12 stages, 2 barriers/stage.
// 32 KB LDS -> up to 5 blocks/CU; cross-block wave overlap hides the barrier drain.
// LDS chunk swizzle: 16B chunk q of row r stored at slot r*8 + (q ^ (r&7)).
#define NSTG 12

__global__ __launch_bounds__(256, 4) void gsa_gemm5(
    const unsigned short* __restrict__ Ag,    // (M,K)
    const unsigned short* __restrict__ WvT,   // (N,K)
    const float* __restrict__ wsB,
    const float* __restrict__ bv,
    float* __restrict__ out)
{
    __shared__ short lds[16384];   // A = [0,8192), B = [8192,16384)  (shorts)

    const int t = threadIdx.x;
    // XCD partition: xcd = L&7 owns m-tiles {xcd, xcd+8, ...}; n varies fastest.
    const int L      = blockIdx.x;
    const int xcd    = L & 7;
    const int grp    = L >> 3;          // 0..77
    const int n_t    = grp % 6;
    const int mchunk = grp / 6;         // 0..12
    const int m_tile = mchunk * 8 + xcd;
    if (m_tile >= 98) return;           // 36 of 624 blocks idle
    const int m0 = m_tile * 128;
    const int n0 = n_t * 128;

    const int lane = t & 63;
    const int w    = t >> 6;

    // ---- staging: per wave 4 A-insts + 4 B-insts of 1KB each ----
    const unsigned short* aSrc[4];
    const unsigned short* bSrc[4];
    int ldsA[4], ldsB[4];
    #pragma unroll
    for (int i = 0; i < 4; ++i) {
        const int rr = (w * 4 + i) * 8 + (lane >> 3);   // row 0..127
        const int qq = (lane & 7) ^ (rr & 7);           // swizzled global chunk
        aSrc[i] = Ag  + (size_t)(m0 + rr) * Dd + qq * 8;
        bSrc[i] = WvT + (size_t)(n0 + rr) * Dd + qq * 8;
        ldsA[i] = (w * 4 + i) * 512;           // shorts (wave-uniform)
        ldsB[i] = 8192 + (w * 4 + i) * 512;
    }

    // ---- MFMA fragment offsets (swizzle-aware) ----
    const int col  = lane & 15;
    const int quad = lane >> 4;
    const int wm   = (w & 1) * 64;
    const int wn   = (w >> 1) * 64;
    int offA[4][2], offB[4][2];
    #pragma unroll
    for (int i = 0; i < 4; ++i) {
        const int ra = wm + i * 16 + col;
        const int rb = wn + i * 16 + col;
        #pragma unroll
        for (int ks = 0; ks < 2; ++ks) {
            offA[i][ks] = (ra * 8 + ((ks * 4 + quad) ^ (ra & 7))) * 8;
            offB[i][ks] = 8192 + (rb * 8 + ((ks * 4 + quad) ^ (rb & 7))) * 8;
        }
    }

    f32x4 acc[4][4];
    #pragma unroll
    for (int i = 0; i < 4; ++i)
        #pragma unroll
        for (int j = 0; j < 4; ++j) acc[i][j] = (f32x4)0.0f;

    for (int s = 0; s < NSTG; ++s) {
        const int kadv = s * 64;
        if (s > 0) __syncthreads();   // prior stage's LDS reads complete before overwrite
        #pragma unroll
        for (int i = 0; i < 4; ++i) {
            gload_lds16(aSrc[i] + kadv, &lds[ldsA[i]]);
            gload_lds16(bSrc[i] + kadv, &lds[ldsB[i]]);
        }
        __syncthreads();              // drains DMA (vmcnt 0) -> tile resident
        #pragma unroll
        for (int ks = 0; ks < 2; ++ks) {
            bf16x8 aF[4], bF[4];
            #pragma unroll
            for (int mi = 0; mi < 4; ++mi)
                aF[mi] = *reinterpret_cast<const bf16x8*>(lds + offA[mi][ks]);
            #pragma unroll
            for (int ni = 0; ni < 4; ++ni)
                bF[ni] = *reinterpret_cast<const bf16x8*>(lds + offB[ni][ks]);
            #pragma unroll
            for (int mi = 0; mi < 4; ++mi)
                #pragma unroll
                for (int ni = 0; ni < 4; ++ni)
                    acc[mi][ni] = __builtin_amdgcn_mfma_f32_16x16x32_bf16(
                        aF[mi], bF[ni], acc[mi][ni], 0, 0, 0);
        }
    }

    // ---- epilogue ----
    float bvv[4];
    #pragma unroll
    for (int ni = 0; ni < 4; ++ni) bvv[ni] = bv[n0 + wn + ni * 16 + col];

    #pragma unroll
    for (int mi = 0; mi < 4; ++mi) {
        #pragma unroll
        for (int rg = 0; rg < 4; ++rg) {
            const int mg = m0 + wm + mi * 16 + quad * 4 + rg;  // C/D row = quad*4+reg
            const int b  = mg / Pp;
            const float wsv = wsB[mg];
            float* orow = out + ((size_t)(mg + b + 1)) * Dd;   // b*197 + 1 + p
            #pragma unroll
            for (int ni = 0; ni < 4; ++ni)
                orow[n0 + wn + ni * 16 + col] = acc[mi][ni][rg] + wsv * bvv[ni];
        }
    }
}

// ================= fallback: round-2 LDS MFMA path (ws >= 1.18MB only) =================
__global__ __launch_bounds__(256) void wv_transpose(
    const float* __restrict__ Wv, unsigned short* __restrict__ WvT)
{
    const int u = blockIdx.x * 256 + threadIdx.x;
    const int o = u * 8;
    const int n = o / Dd;
    const int k = o - n * Dd;
    bf16x8 tv;
    #pragma unroll
    for (int j = 0; j < 8; ++j) tv[j] = (short)f2bf(Wv[(size_t)(k + j) * Dd + n]);
    *reinterpret_cast<bf16x8*>(WvT + o) = tv;
}

__global__ __launch_bounds__(256) void gsa_fill_cls(float* __restrict__ out) {
    const int idx = blockIdx.x * 256 + threadIdx.x;
    if (idx < Bb * Dd) {
        const int b = idx / Dd;
        const int d = idx - b * Dd;
        out[(size_t)b * Ss * Dd + d] = 1.0f;
    }
}

__global__ __launch_bounds__(256, 2) void gsa_mfma(
    const float* __restrict__ x, const int* __restrict__ img_ids,
    const unsigned short* __restrict__ WvT, const float* __restrict__ bv,
    const float* __restrict__ avgs, const float* __restrict__ stds,
    const float* __restrict__ noise, float* __restrict__ out)
{
    __shared__ short As[128][40];
    __shared__ short Bs[128][40];
    __shared__ float wsums[128];
    const int t  = threadIdx.x;
    const int m0 = blockIdx.x * 128;
    const int n0 = blockIdx.y * 128;
    const int r  = t >> 1;
    const int kh = t & 1;
    const int ko = kh * 16;
    float w0, w1, w2, w3;
    const float *sA0, *sA1, *sA2, *sA3;
    {
        const int m = m0 + r, b = m / Pp, p = m - b * Pp;
        GParams g = gather_params(img_ids, avgs, stds, noise, b, p);
        w0 = g.w0; w1 = g.w1; w2 = g.w2; w3 = g.w3;
        const size_t xb = (size_t)b * Ss;
        sA0 = x + (xb + g.i0) * Dd + ko;
        sA1 = x + (xb + g.i1) * Dd + ko;
        sA2 = x + (xb + g.i2) * Dd + ko;
        sA3 = x + (xb + g.i3) * Dd + ko;
        if (kh == 0) wsums[r] = w0 + w1 + w2 + w3;
    }
    const unsigned short* srcB = WvT + (size_t)(n0 + r) * Dd + ko;
    const int lane = t & 63, wv = t >> 6;
    const int col = lane & 15, quad = lane >> 4;
    const int wm = (wv & 1) * 64, wn = (wv >> 1) * 64;
    const short* aptr[4];
    const short* bptr[4];
    #pragma unroll
    for (int mi = 0; mi < 4; ++mi) aptr[mi] = &As[wm + mi * 16 + col][quad * 8];
    #pragma unroll
    for (int ni = 0; ni < 4; ++ni) bptr[ni] = &Bs[wn + ni * 16 + col][quad * 8];
    f32x4 acc[4][4];
    #pragma unroll
    for (int i = 0; i < 4; ++i)
        #pragma unroll
        for (int j = 0; j < 4; ++j) acc[i][j] = (f32x4)0.0f;
    #pragma unroll 1
    for (int kt = 0; kt < Dd; kt += 32) {
        F4 l0[4], l1[4], l2[4], l3[4];
        #pragma unroll
        for (int c = 0; c < 4; ++c) {
            l0[c] = *reinterpret_cast<const F4*>(sA0 + kt + c * 4);
            l1[c] = *reinterpret_cast<const F4*>(sA1 + kt + c * 4);
            l2[c] = *reinterpret_cast<const F4*>(sA2 + kt + c * 4);
            l3[c] = *reinterpret_cast<const F4*>(sA3 + kt + c * 4);
        }
        bf16x8 b0 = *reinterpret_cast<const bf16x8*>(srcB + kt);
        bf16x8 b1 = *reinterpret_cast<const bf16x8*>(srcB + kt + 8);
        bf16x8 ua0, ua1;
        #pragma unroll
        for (int e = 0; e < 8; ++e) {
            const int c = e >> 2, q = e & 3;
            ua0[e] = (short)f2bf(w0*l0[c].v[q] + w1*l1[c].v[q] + w2*l2[c].v[q] + w3*l3[c].v[q]);
        }
        #pragma unroll
        for (int e = 0; e < 8; ++e) {
            const int c = (e + 8) >> 2, q = e & 3;
            ua1[e] = (short)f2bf(w0*l0[c].v[q] + w1*l1[c].v[q] + w2*l2[c].v[q] + w3*l3[c].v[q]);
        }
        __syncthreads();
        *reinterpret_cast<bf16x8*>(&As[r][ko])     = ua0;
        *reinterpret_cast<bf16x8*>(&As[r][ko + 8]) = ua1;
        *reinterpret_cast<bf16x8*>(&Bs[r][ko])     = b0;
        *reinterpret_cast<bf16x8*>(&Bs[r][ko + 8]) = b1;
        __syncthreads();
        bf16x8 aF[4], bF[4];
        #pragma unroll
        for (int mi = 0; mi < 4; ++mi) aF[mi] = *reinterpret_cast<const bf16x8*>(aptr[mi]);
        #pragma unroll
        for (int ni = 0; ni < 4; ++ni) bF[ni] = *reinterpret_cast<const bf16x8*>(bptr[ni]);
        #pragma unroll
        for (int mi = 0; mi < 4; ++mi)
            #pragma unroll
            for (int ni = 0; ni < 4; ++ni)
                acc[mi][ni] = __builtin_amdgcn_mfma_f32_16x16x32_bf16(
                    aF[mi], bF[ni], acc[mi][ni], 0, 0, 0);
    }
    float bvv[4];
    #pragma unroll
    for (int ni = 0; ni < 4; ++ni) bvv[ni] = bv[n0 + wn + ni * 16 + col];
    #pragma unroll
    for (int mi = 0; mi < 4; ++mi) {
        #pragma unroll
        for (int rg = 0; rg < 4; ++rg) {
            const int ml = wm + mi * 16 + quad * 4 + rg;
            const int mg = m0 + ml;
            const int b  = mg / Pp;
            const float wsv = wsums[ml];
            float* orow = out + ((size_t)(mg + b + 1)) * Dd;
            #pragma unroll
            for (int ni = 0; ni < 4; ++ni)
                orow[n0 + wn + ni * 16 + col] = acc[mi][ni][rg] + wsv * bvv[ni];
        }
    }
}

extern "C" void kernel_launch(void* const* d_in, const int* in_sizes, int n_in,
                              void* d_out, int out_size, void* d_ws, size_t ws_size,
                              hipStream_t stream) {
    // order: x, img_ids, mask, Wq, bq, Wk, bk, Wv, bv, avgs, std_devs, noise
    const float* x       = (const float*)d_in[0];
    const int*   img_ids = (const int*)  d_in[1];
    const float* Wv      = (const float*)d_in[7];
    const float* bv      = (const float*)d_in[8];
    const float* avgs    = (const float*)d_in[9];
    const float* stds    = (const float*)d_in[10];
    const float* noise   = (const float*)d_in[11];
    float* out = (float*)d_out;

    const size_t ag_bytes  = (size_t)Bb * Pp * Dd * sizeof(unsigned short); // 19.27 MB
    const size_t wvt_bytes = (size_t)Dd * Dd * sizeof(unsigned short);      // 1.18 MB
    const size_t ws_need   = ag_bytes + wvt_bytes + (size_t)Bb * Pp * sizeof(float);

    if (d_ws != nullptr && ws_size >= ws_need) {
        unsigned short* Ag  = (unsigned short*)d_ws;
        unsigned short* WvT = (unsigned short*)((char*)d_ws + ag_bytes);
        float*          wsB = (float*)((char*)d_ws + ag_bytes + wvt_bytes);
        gsa_prep<<<GATHER_BLKS + TRANS_BLKS + CLS_BLKS, 256, 0, stream>>>(
            x, img_ids, Wv, avgs, stds, noise, Ag, WvT, wsB, out);
        gsa_gemm5<<<624, 256, 0, stream>>>(Ag, WvT, wsB, bv, out);  // 13*6*8, XCD-swizzled
    } else {
        unsigned short* WvT = (unsigned short*)d_ws;
        gsa_fill_cls<<<(Bb * Dd + 255) / 256, 256, 0, stream>>>(out);
        wv_transpose<<<(Dd * Dd / 8) / 256, 256, 0, stream>>>(Wv, WvT);
        dim3 grid((Bb * Pp) / 128, Dd / 128);
        gsa_mfma<<<grid, 256, 0, stream>>>(x, img_ids, WvT, bv, avgs, stds, noise, out);
    }
}